// Round 2
// baseline (2384.596 us; speedup 1.0000x reference)
//
#include <hip/hip_runtime.h>
#include <stdint.h>

// GCN multi-branch: per branch b, twice: H = relu((L_b @ X) @ W + bias)
// Big GEMM: M=8192 (nodes out), K=8192 (nodes in), N=512 (4 batches x 128 feat)
// bf16 MFMA 16x16x32, 128x128 tile, 4 waves (2x2), dbuf LDS, fused W-transform epilogue.
// d_out is FLOAT32 (reference output dtype); intermediates in ws are bf16.

typedef short bf16x8 __attribute__((ext_vector_type(8)));   // 8 bf16 in 4 VGPRs (guide-verified operand type)
typedef float f32x4 __attribute__((ext_vector_type(4)));

static __device__ __forceinline__ unsigned short f2bf(float f) {
  __bf16 h = (__bf16)f;
  return __builtin_bit_cast(unsigned short, h);
}
static __device__ __forceinline__ unsigned int pack2(float a, float b) {
  return (unsigned int)f2bf(a) | ((unsigned int)f2bf(b) << 16);
}

#define LDA_PITCH 40   // 32 bf16 + 8 pad -> 80B rows, conflict-free b128 column-of-rows reads
#define ABUF      5120 // 128*40 elems per buffer

// ---------------------------------------------------------------- prep: X -> XcT bf16 [512][8192]
__global__ __launch_bounds__(256)
void prep_x(const float* __restrict__ x, unsigned short* __restrict__ xct) {
  __shared__ float tile[64][129];
  const int t  = threadIdx.x;
  const int m0 = blockIdx.x * 64;
  const int b  = blockIdx.y;
  const float* src = x + (size_t)b * (8192 * 128) + (size_t)m0 * 128;
#pragma unroll
  for (int i = 0; i < 32; ++i) {
    int e = t + i * 256;
    tile[e >> 7][e & 127] = src[e];
  }
  __syncthreads();
  const int f    = t >> 1;
  const int mseg = (t & 1) * 32;
  unsigned short* dst = xct + (size_t)(b * 128 + f) * 8192 + m0 + mseg;
#pragma unroll
  for (int i = 0; i < 4; ++i) {
    uint4 v;
    v.x = pack2(tile[mseg + i * 8 + 0][f], tile[mseg + i * 8 + 1][f]);
    v.y = pack2(tile[mseg + i * 8 + 2][f], tile[mseg + i * 8 + 3][f]);
    v.z = pack2(tile[mseg + i * 8 + 4][f], tile[mseg + i * 8 + 5][f]);
    v.w = pack2(tile[mseg + i * 8 + 6][f], tile[mseg + i * 8 + 7][f]);
    ((uint4*)dst)[i] = v;
  }
}

// ---------------------------------------------------------------- prep: W[fi][fo] -> WT bf16 [fo][fi]
struct WPtrs { const float* w[8]; };
__global__ __launch_bounds__(256)
void prep_w(WPtrs p, unsigned short* __restrict__ wt) {
  const int s = blockIdx.x;
  const float* W = p.w[s];
  unsigned short* dst = wt + s * 16384;
  for (int i = threadIdx.x; i < 16384; i += 256) {
    const int fi = i >> 7, fo = i & 127;
    dst[fo * 128 + fi] = f2bf(W[i]);
  }
}

// ---------------------------------------------------------------- fused GEMM + feature transform
// LAYER 0: Dst = H1T bf16 [512][8192] (n-major for next GEMM's B operand)
// LAYER 1: Dst = float* out + branch offset, layout [batch][node][feat] FP32
template <int LAYER>
__global__ __launch_bounds__(256)
void gcn_gemm(const float* __restrict__ A,              // L [8192][8192] f32
              const unsigned short* __restrict__ Bsrc,  // [512][8192] bf16, n-major
              const unsigned short* __restrict__ WT,    // [128][128] bf16, (fo, fi)
              const float* __restrict__ bias,           // [128] f32
              void* __restrict__ DstV) {
  extern __shared__ char smem[];
  unsigned short* Al = (unsigned short*)smem;  // [2][128][40]
  unsigned short* Bl = Al + 2 * ABUF;          // [2][128][40]

  const int t    = threadIdx.x;
  const int lane = t & 63;
  const int l15  = lane & 15;
  const int lk   = (lane >> 4) * 8;            // k-offset: same mapping for A and B (permutation cancels)
  const int wave = t >> 6;
  const int wm   = (wave >> 1) * 64;
  const int wn   = (wave & 1) * 64;
  const int mbase = blockIdx.x * 128;
  const int nb    = blockIdx.y;

  // staging: thread -> (row, 16-elem half)
  const int srow  = t >> 1;
  const int shalf = (t & 1) * 16;
  const float*          aP = A    + (size_t)(mbase + srow) * 8192 + shalf;
  const unsigned short* bP = Bsrc + (size_t)(nb * 128 + srow) * 8192 + shalf;
  unsigned short* aW = Al + srow * LDA_PITCH + shalf;
  unsigned short* bW = Bl + srow * LDA_PITCH + shalf;

  f32x4 acc[4][4];
#pragma unroll
  for (int i = 0; i < 4; ++i)
#pragma unroll
    for (int j = 0; j < 4; ++j) acc[i][j] = f32x4{0.f, 0.f, 0.f, 0.f};

  float4 aR[4];
  uint4  bR[2];

  // prologue: stage k-tile 0 into buffer 0
  {
    const float4* p = (const float4*)aP;
    aR[0] = p[0]; aR[1] = p[1]; aR[2] = p[2]; aR[3] = p[3];
    const uint4* q = (const uint4*)bP;
    bR[0] = q[0]; bR[1] = q[1];
    uint4 v0, v1;
    v0.x = pack2(aR[0].x, aR[0].y); v0.y = pack2(aR[0].z, aR[0].w);
    v0.z = pack2(aR[1].x, aR[1].y); v0.w = pack2(aR[1].z, aR[1].w);
    v1.x = pack2(aR[2].x, aR[2].y); v1.y = pack2(aR[2].z, aR[2].w);
    v1.z = pack2(aR[3].x, aR[3].y); v1.w = pack2(aR[3].z, aR[3].w);
    *(uint4*)aW = v0; *(uint4*)(aW + 8) = v1;
    *(uint4*)bW = bR[0]; *(uint4*)(bW + 8) = bR[1];
  }
  __syncthreads();

  for (int tt = 0; tt < 256; ++tt) {
    const int cur = tt & 1;
    if (tt < 255) {  // issue next tile's global loads early; latency hides under MFMA
      const float4* p = (const float4*)(aP + (tt + 1) * 32);
      aR[0] = p[0]; aR[1] = p[1]; aR[2] = p[2]; aR[3] = p[3];
      const uint4* q = (const uint4*)(bP + (tt + 1) * 32);
      bR[0] = q[0]; bR[1] = q[1];
    }
    {
      bf16x8 av[4], bv[4];
      const unsigned short* ab = Al + cur * ABUF;
      const unsigned short* bb = Bl + cur * ABUF;
#pragma unroll
      for (int mi = 0; mi < 4; ++mi)
        av[mi] = *(const bf16x8*)(ab + (wm + mi * 16 + l15) * LDA_PITCH + lk);
#pragma unroll
      for (int ni = 0; ni < 4; ++ni)
        bv[ni] = *(const bf16x8*)(bb + (wn + ni * 16 + l15) * LDA_PITCH + lk);
#pragma unroll
      for (int mi = 0; mi < 4; ++mi)
#pragma unroll
        for (int ni = 0; ni < 4; ++ni)
          acc[mi][ni] = __builtin_amdgcn_mfma_f32_16x16x32_bf16(av[mi], bv[ni], acc[mi][ni], 0, 0, 0);
    }
    __syncthreads();
    if (tt < 255) {
      const int nxt = cur ^ 1;
      uint4 v0, v1;
      v0.x = pack2(aR[0].x, aR[0].y); v0.y = pack2(aR[0].z, aR[0].w);
      v0.z = pack2(aR[1].x, aR[1].y); v0.w = pack2(aR[1].z, aR[1].w);
      v1.x = pack2(aR[2].x, aR[2].y); v1.y = pack2(aR[2].z, aR[2].w);
      v1.z = pack2(aR[3].x, aR[3].y); v1.w = pack2(aR[3].z, aR[3].w);
      *(uint4*)(aW + nxt * ABUF) = v0; *(uint4*)(aW + nxt * ABUF + 8) = v1;
      *(uint4*)(bW + nxt * ABUF) = bR[0]; *(uint4*)(bW + nxt * ABUF + 8) = bR[1];
    }
    __syncthreads();
  }

  // ---------------- epilogue: H = relu(S @ W + bias), S = acc (bf16 via LDS round-trip)
  unsigned short* S  = (unsigned short*)smem;  // [128][128] (reuses loop buffers; barrier already passed)
  unsigned short* Wl = S + 16384;              // [128][128]
#pragma unroll
  for (int mi = 0; mi < 4; ++mi) {
#pragma unroll
    for (int ni = 0; ni < 4; ++ni) {
      const int row0 = wm + mi * 16 + (lane >> 4) * 4;
      const int col  = wn + ni * 16 + l15;
#pragma unroll
      for (int r = 0; r < 4; ++r) S[(row0 + r) * 128 + col] = f2bf(acc[mi][ni][r]);
    }
  }
  {
    const int fo = t >> 1, seg = (t & 1) * 64;
    const uint4* src = (const uint4*)(WT + fo * 128 + seg);
    uint4* dst = (uint4*)(Wl + fo * 128 + seg);
#pragma unroll
    for (int i = 0; i < 8; ++i) dst[i] = src[i];
  }
  __syncthreads();

  f32x4 acc2[4][4];
#pragma unroll
  for (int ni = 0; ni < 4; ++ni) {
    const float bvv = bias[wn + ni * 16 + l15];
#pragma unroll
    for (int mi = 0; mi < 4; ++mi) acc2[mi][ni] = f32x4{bvv, bvv, bvv, bvv};
  }
#pragma unroll
  for (int kk = 0; kk < 4; ++kk) {
    bf16x8 av[4], wv[4];
#pragma unroll
    for (int mi = 0; mi < 4; ++mi)
      av[mi] = *(const bf16x8*)(S + (wm + mi * 16 + l15) * 128 + kk * 32 + lk);
#pragma unroll
    for (int ni = 0; ni < 4; ++ni)
      wv[ni] = *(const bf16x8*)(Wl + (wn + ni * 16 + l15) * 128 + kk * 32 + lk);
#pragma unroll
    for (int mi = 0; mi < 4; ++mi)
#pragma unroll
      for (int ni = 0; ni < 4; ++ni)
        acc2[mi][ni] = __builtin_amdgcn_mfma_f32_16x16x32_bf16(av[mi], wv[ni], acc2[mi][ni], 0, 0, 0);
  }

#pragma unroll
  for (int mi = 0; mi < 4; ++mi) {
#pragma unroll
    for (int ni = 0; ni < 4; ++ni) {
      const int row0 = wm + mi * 16 + (lane >> 4) * 4;
      const int col  = wn + ni * 16 + l15;
      const float v0 = fmaxf(acc2[mi][ni][0], 0.f);
      const float v1 = fmaxf(acc2[mi][ni][1], 0.f);
      const float v2 = fmaxf(acc2[mi][ni][2], 0.f);
      const float v3 = fmaxf(acc2[mi][ni][3], 0.f);
      if (LAYER == 0) {
        unsigned short* Dst = (unsigned short*)DstV;
        uint2 pv;
        pv.x = pack2(v0, v1);
        pv.y = pack2(v2, v3);
        *(uint2*)(Dst + (size_t)(nb * 128 + col) * 8192 + mbase + row0) = pv;
      } else {
        float* Dst = (float*)DstV;   // fp32 output buffer (reference output dtype)
        const size_t base = (size_t)nb * 1048576 + (size_t)(mbase + row0) * 128 + col;
        Dst[base      ] = v0;
        Dst[base + 128] = v1;
        Dst[base + 256] = v2;
        Dst[base + 384] = v3;
      }
    }
  }
}

// ---------------------------------------------------------------- launch
extern "C" void kernel_launch(void* const* d_in, const int* in_sizes, int n_in,
                              void* d_out, int out_size, void* d_ws, size_t ws_size,
                              hipStream_t stream) {
  // inputs: 0:x 1:L0 2:L1 3:L2 4:L3 then (W{b}{l}, b{b}{l}) pairs: W at 5+b*4+l*2, bias at 6+b*4+l*2
  const float* x = (const float*)d_in[0];
  unsigned short* XcT = (unsigned short*)d_ws;           // [512][8192] bf16 (8 MiB)
  unsigned short* H1T = XcT + (size_t)512 * 8192;        // [512][8192] bf16 (8 MiB)
  unsigned short* WT  = H1T + (size_t)512 * 8192;        // [8][128][128] bf16 (256 KiB)
  float* out = (float*)d_out;                            // FP32 outputs, 4 x [4][8192][128]

  prep_x<<<dim3(128, 4), 256, 0, stream>>>(x, XcT);

  WPtrs wp;
  for (int b = 0; b < 4; ++b) {
    wp.w[b * 2 + 0] = (const float*)d_in[5 + b * 4 + 0];
    wp.w[b * 2 + 1] = (const float*)d_in[5 + b * 4 + 2];
  }
  prep_w<<<8, 256, 0, stream>>>(wp, WT);

  const size_t shmem = 65536;  // loop: 2*(128*40)*2*2B = 40KB; epilogue: 2*32KB = 64KB
  for (int b = 0; b < 4; ++b) {
    const float* L  = (const float*)d_in[1 + b];
    const float* b0 = (const float*)d_in[6 + b * 4];
    const float* b1 = (const float*)d_in[8 + b * 4];
    gcn_gemm<0><<<dim3(64, 4), 256, shmem, stream>>>(L, XcT, WT + (2 * b) * 16384, b0, (void*)H1T);
    gcn_gemm<1><<<dim3(64, 4), 256, shmem, stream>>>(L, H1T, WT + (2 * b + 1) * 16384, b1,
                                                     (void*)(out + (size_t)b * 4194304));
  }
}

// Round 3
// 1585.675 us; speedup vs baseline: 1.5038x; 1.5038x over previous
//
#include <hip/hip_runtime.h>
#include <stdint.h>

// GCN multi-branch: per branch b, twice: H = relu((L_b @ X) @ W + bias)
// Round 3: split-K=4 (grid 1024 = 4 blocks/CU), GEMM LDS 32KB linear layout,
// B staged via global_load_lds, reduce+W-transform fused in a second kernel.

typedef short bf16x8 __attribute__((ext_vector_type(8)));
typedef float f32x4 __attribute__((ext_vector_type(4)));

static __device__ __forceinline__ unsigned short f2bf(float f) {
  __bf16 h = (__bf16)f;
  return __builtin_bit_cast(unsigned short, h);
}
static __device__ __forceinline__ unsigned int pack2(float a, float b) {
  return (unsigned int)f2bf(a) | ((unsigned int)f2bf(b) << 16);
}

#define GLOAD16(g, l)                                                              \
  __builtin_amdgcn_global_load_lds((const __attribute__((address_space(1))) void*)(g), \
                                   (__attribute__((address_space(3))) void*)(l), 16, 0, 0)

// ---------------------------------------------------------------- prep: X -> XcT bf16 [512][8192]
__global__ __launch_bounds__(256)
void prep_x(const float* __restrict__ x, unsigned short* __restrict__ xct) {
  __shared__ float tile[64][129];
  const int t  = threadIdx.x;
  const int m0 = blockIdx.x * 64;
  const int b  = blockIdx.y;
  const float* src = x + (size_t)b * (8192 * 128) + (size_t)m0 * 128;
#pragma unroll
  for (int i = 0; i < 32; ++i) {
    int e = t + i * 256;
    tile[e >> 7][e & 127] = src[e];
  }
  __syncthreads();
  const int f    = t >> 1;
  const int mseg = (t & 1) * 32;
  unsigned short* dst = xct + (size_t)(b * 128 + f) * 8192 + m0 + mseg;
#pragma unroll
  for (int i = 0; i < 4; ++i) {
    uint4 v;
    v.x = pack2(tile[mseg + i * 8 + 0][f], tile[mseg + i * 8 + 1][f]);
    v.y = pack2(tile[mseg + i * 8 + 2][f], tile[mseg + i * 8 + 3][f]);
    v.z = pack2(tile[mseg + i * 8 + 4][f], tile[mseg + i * 8 + 5][f]);
    v.w = pack2(tile[mseg + i * 8 + 6][f], tile[mseg + i * 8 + 7][f]);
    ((uint4*)dst)[i] = v;
  }
}

// ---------------------------------------------------------------- prep: W[fi][fo] -> WT bf16 [fo][fi]
struct WPtrs { const float* w[8]; };
__global__ __launch_bounds__(256)
void prep_w(WPtrs p, unsigned short* __restrict__ wt) {
  const int s = blockIdx.x;
  const float* W = p.w[s];
  unsigned short* dst = wt + s * 16384;
  for (int i = threadIdx.x; i < 16384; i += 256) {
    const int fi = i >> 7, fo = i & 127;
    dst[fo * 128 + fi] = f2bf(W[i]);
  }
}

// ---------------------------------------------------------------- split-K GEMM: partial = L_tile @ B^T
// A: L fp32 [8192][8192]; B: bf16 [512][8192] n-major; Part: fp32 [4][8192][512]
__global__ __launch_bounds__(256, 4)
void gemm_splitk(const float* __restrict__ A, const unsigned short* __restrict__ Bsrc,
                 float* __restrict__ Part) {
  __shared__ unsigned short Al[2][128 * 32];  // linear: 64B rows -> even bank spread on b128 reads
  __shared__ unsigned short Bl[2][128 * 32];

  const int t = threadIdx.x, lane = t & 63, wave = t >> 6;
  const int l15 = lane & 15, lk = (lane >> 4) * 8;
  const int wm = (wave >> 1) * 64, wn = (wave & 1) * 64;
  const int mbase = blockIdx.x * 128, nb = blockIdx.y, ks = blockIdx.z;
  const int k0 = ks * 2048;  // 64 iters of BK=32

  // A staging: thread -> row t>>1, 16 elems at (t&1)*16 (fp32 -> bf16 in regs)
  const int arow = t >> 1, acol = (t & 1) * 16;
  const float* aP = A + (size_t)(mbase + arow) * 8192 + k0 + acol;

  // B staging: global_load_lds; wave stages rows [wave*32, wave*32+32) in 2 instrs;
  // lane l deposits at ldsbase + l*16B -> row +l/4, k-elems (l%4)*8 (matches global addr below)
  const unsigned short* bg =
      Bsrc + (size_t)(nb * 128 + wave * 32 + (lane >> 2)) * 8192 + k0 + (lane & 3) * 8;

  f32x4 acc[4][4];
#pragma unroll
  for (int i = 0; i < 4; ++i)
#pragma unroll
    for (int j = 0; j < 4; ++j) acc[i][j] = f32x4{0.f, 0.f, 0.f, 0.f};

  // prologue: stage k-step 0 into buffer 0
  {
    GLOAD16(bg, &Bl[0][(wave * 32) * 32]);
    GLOAD16(bg + 16 * 8192, &Bl[0][(wave * 32 + 16) * 32]);
    const float4* p = (const float4*)aP;
    float4 a0 = p[0], a1 = p[1], a2 = p[2], a3 = p[3];
    uint4 w0, w1;
    w0.x = pack2(a0.x, a0.y); w0.y = pack2(a0.z, a0.w);
    w0.z = pack2(a1.x, a1.y); w0.w = pack2(a1.z, a1.w);
    w1.x = pack2(a2.x, a2.y); w1.y = pack2(a2.z, a2.w);
    w1.z = pack2(a3.x, a3.y); w1.w = pack2(a3.z, a3.w);
    *(uint4*)&Al[0][arow * 32 + acol]     = w0;
    *(uint4*)&Al[0][arow * 32 + acol + 8] = w1;
  }
  __syncthreads();

  for (int tt = 0; tt < 64; ++tt) {
    const int cur = tt & 1, nxt = cur ^ 1;
    float4 a0, a1, a2, a3;
    if (tt < 63) {  // issue next-tile loads early; latency hides under MFMA phase
      GLOAD16(bg + (size_t)(tt + 1) * 32, &Bl[nxt][(wave * 32) * 32]);
      GLOAD16(bg + (size_t)(tt + 1) * 32 + 16 * 8192, &Bl[nxt][(wave * 32 + 16) * 32]);
      const float4* p = (const float4*)(aP + (tt + 1) * 32);
      a0 = p[0]; a1 = p[1]; a2 = p[2]; a3 = p[3];
    }
    {
      bf16x8 av[4], bv[4];
#pragma unroll
      for (int mi = 0; mi < 4; ++mi)
        av[mi] = *(const bf16x8*)&Al[cur][(wm + mi * 16 + l15) * 32 + lk];
#pragma unroll
      for (int ni = 0; ni < 4; ++ni)
        bv[ni] = *(const bf16x8*)&Bl[cur][(wn + ni * 16 + l15) * 32 + lk];
#pragma unroll
      for (int mi = 0; mi < 4; ++mi)
#pragma unroll
        for (int ni = 0; ni < 4; ++ni)
          acc[mi][ni] = __builtin_amdgcn_mfma_f32_16x16x32_bf16(av[mi], bv[ni], acc[mi][ni], 0, 0, 0);
    }
    if (tt < 63) {
      uint4 w0, w1;
      w0.x = pack2(a0.x, a0.y); w0.y = pack2(a0.z, a0.w);
      w0.z = pack2(a1.x, a1.y); w0.w = pack2(a1.z, a1.w);
      w1.x = pack2(a2.x, a2.y); w1.y = pack2(a2.z, a2.w);
      w1.z = pack2(a3.x, a3.y); w1.w = pack2(a3.z, a3.w);
      *(uint4*)&Al[nxt][arow * 32 + acol]     = w0;
      *(uint4*)&Al[nxt][arow * 32 + acol + 8] = w1;
    }
    __syncthreads();
  }

  // store fp32 partial tile (verified C/D mapping: col=lane&15, row=(lane>>4)*4+r)
  float* P = Part + ((size_t)ks * 8192 + mbase) * 512 + nb * 128;
#pragma unroll
  for (int mi = 0; mi < 4; ++mi) {
#pragma unroll
    for (int ni = 0; ni < 4; ++ni) {
      const int row0 = wm + mi * 16 + (lane >> 4) * 4;
      const int col  = wn + ni * 16 + l15;
#pragma unroll
      for (int r = 0; r < 4; ++r) P[(size_t)(row0 + r) * 512 + col] = acc[mi][ni][r];
    }
  }
}

// ---------------------------------------------------------------- reduce 4 partials + W-transform
// LAYER 0: Dst = H1T bf16 [512][8192]; LAYER 1: Dst = fp32 out [4][8192][128]
template <int LAYER>
__global__ __launch_bounds__(256)
void reduce_wtrans(const float* __restrict__ Part, const unsigned short* __restrict__ WT,
                   const float* __restrict__ bias, void* __restrict__ DstV) {
  __shared__ unsigned short S[128 * 136];  // +8 pad: 272B rows -> 2-way banks (free), 16B aligned

  const int t = threadIdx.x, lane = t & 63, wave = t >> 6;
  const int l15 = lane & 15, lk = (lane >> 4) * 8;
  const int wm = (wave >> 1) * 64, wn = (wave & 1) * 64;
  const int mbase = blockIdx.x * 128, nb = blockIdx.y;

  const float* P0 = Part + (size_t)mbase * 512 + nb * 128;
#pragma unroll
  for (int rep = 0; rep < 16; ++rep) {
    const int flat4 = rep * 256 + t;
    const int row = flat4 >> 5, c4 = (flat4 & 31) * 4;
    const float* p = P0 + (size_t)row * 512 + c4;
    float4 s0 = *(const float4*)(p);
    float4 s1 = *(const float4*)(p + (size_t)8192 * 512);
    float4 s2 = *(const float4*)(p + (size_t)2 * 8192 * 512);
    float4 s3 = *(const float4*)(p + (size_t)3 * 8192 * 512);
    const float x0 = s0.x + s1.x + s2.x + s3.x;
    const float x1 = s0.y + s1.y + s2.y + s3.y;
    const float x2 = s0.z + s1.z + s2.z + s3.z;
    const float x3 = s0.w + s1.w + s2.w + s3.w;
    uint2 pv;
    pv.x = pack2(x0, x1);
    pv.y = pack2(x2, x3);
    *(uint2*)&S[row * 136 + c4] = pv;
  }
  __syncthreads();

  f32x4 acc2[4][4];
#pragma unroll
  for (int ni = 0; ni < 4; ++ni) {
    const float bvv = bias[wn + ni * 16 + l15];
#pragma unroll
    for (int mi = 0; mi < 4; ++mi) acc2[mi][ni] = f32x4{bvv, bvv, bvv, bvv};
  }
#pragma unroll
  for (int kk = 0; kk < 4; ++kk) {
    bf16x8 av[4], wv[4];
#pragma unroll
    for (int mi = 0; mi < 4; ++mi)
      av[mi] = *(const bf16x8*)&S[(wm + mi * 16 + l15) * 136 + kk * 32 + lk];
#pragma unroll
    for (int ni = 0; ni < 4; ++ni)  // W fragments straight from global (L2-hot, 32KB)
      wv[ni] = *(const bf16x8*)&WT[(wn + ni * 16 + l15) * 128 + kk * 32 + lk];
#pragma unroll
    for (int mi = 0; mi < 4; ++mi)
#pragma unroll
      for (int ni = 0; ni < 4; ++ni)
        acc2[mi][ni] = __builtin_amdgcn_mfma_f32_16x16x32_bf16(av[mi], wv[ni], acc2[mi][ni], 0, 0, 0);
  }

#pragma unroll
  for (int mi = 0; mi < 4; ++mi) {
#pragma unroll
    for (int ni = 0; ni < 4; ++ni) {
      const int row0 = wm + mi * 16 + (lane >> 4) * 4;
      const int col  = wn + ni * 16 + l15;
      const float v0 = fmaxf(acc2[mi][ni][0], 0.f);
      const float v1 = fmaxf(acc2[mi][ni][1], 0.f);
      const float v2 = fmaxf(acc2[mi][ni][2], 0.f);
      const float v3 = fmaxf(acc2[mi][ni][3], 0.f);
      if (LAYER == 0) {
        unsigned short* Dst = (unsigned short*)DstV;
        uint2 pv;
        pv.x = pack2(v0, v1);
        pv.y = pack2(v2, v3);
        *(uint2*)(Dst + (size_t)(nb * 128 + col) * 8192 + mbase + row0) = pv;
      } else {
        float* Dst = (float*)DstV;
        const size_t base = (size_t)nb * 1048576 + (size_t)(mbase + row0) * 128 + col;
        Dst[base      ] = v0;
        Dst[base + 128] = v1;
        Dst[base + 256] = v2;
        Dst[base + 384] = v3;
      }
    }
  }
}

// ---------------------------------------------------------------- launch
extern "C" void kernel_launch(void* const* d_in, const int* in_sizes, int n_in,
                              void* d_out, int out_size, void* d_ws, size_t ws_size,
                              hipStream_t stream) {
  const float* x = (const float*)d_in[0];
  unsigned short* XcT = (unsigned short*)d_ws;           // [512][8192] bf16 (8 MiB)
  unsigned short* H1T = XcT + (size_t)512 * 8192;        // [512][8192] bf16 (8 MiB)
  unsigned short* WT  = H1T + (size_t)512 * 8192;        // [8][128][128] bf16 (256 KiB)
  float* Part = (float*)(WT + 8 * 16384);                // [4][8192][512] fp32 (64 MiB)
  float* out = (float*)d_out;                            // FP32 outputs, 4 x [4][8192][128]

  prep_x<<<dim3(128, 4), 256, 0, stream>>>(x, XcT);

  WPtrs wp;
  for (int b = 0; b < 4; ++b) {
    wp.w[b * 2 + 0] = (const float*)d_in[5 + b * 4 + 0];
    wp.w[b * 2 + 1] = (const float*)d_in[5 + b * 4 + 2];
  }
  prep_w<<<8, 256, 0, stream>>>(wp, WT);

  for (int b = 0; b < 4; ++b) {
    const float* L  = (const float*)d_in[1 + b];
    const float* b0 = (const float*)d_in[6 + b * 4];
    const float* b1 = (const float*)d_in[8 + b * 4];
    gemm_splitk<<<dim3(64, 4, 4), 256, 0, stream>>>(L, XcT, Part);
    reduce_wtrans<0><<<dim3(64, 4), 256, 0, stream>>>(Part, WT + (2 * b) * 16384, b0, (void*)H1T);
    gemm_splitk<<<dim3(64, 4, 4), 256, 0, stream>>>(L, H1T, Part);
    reduce_wtrans<1><<<dim3(64, 4), 256, 0, stream>>>(Part, WT + (2 * b + 1) * 16384, b1,
                                                      (void*)(out + (size_t)b * 4194304));
  }
}

// Round 4
// 1184.919 us; speedup vs baseline: 2.0125x; 1.3382x over previous
//
#include <hip/hip_runtime.h>
#include <stdint.h>

// GCN multi-branch: per branch b, twice: H = relu((L_b @ X) @ W + bias)
// Round 4: branch-fused single dispatch per layer (grid 64x4x4 = 1024 blocks = 4/CU),
// A (fp32) staged via global_load_lds with XOR chunk-swizzle (pre-swizzled global src),
// bf16 cvt at fragment read; B bf16 gl_lds swizzled; fused W-transform epilogue.

typedef short bf16x8 __attribute__((ext_vector_type(8)));
typedef float f32x4 __attribute__((ext_vector_type(4)));

static __device__ __forceinline__ unsigned short f2bf(float f) {
  __bf16 h = (__bf16)f;
  return __builtin_bit_cast(unsigned short, h);
}
static __device__ __forceinline__ unsigned int pack2(float a, float b) {
  return (unsigned int)f2bf(a) | ((unsigned int)f2bf(b) << 16);
}
static __device__ __forceinline__ bf16x8 cvt8(f32x4 lo, f32x4 hi) {
  bf16x8 r;
  r[0] = (short)f2bf(lo[0]); r[1] = (short)f2bf(lo[1]);
  r[2] = (short)f2bf(lo[2]); r[3] = (short)f2bf(lo[3]);
  r[4] = (short)f2bf(hi[0]); r[5] = (short)f2bf(hi[1]);
  r[6] = (short)f2bf(hi[2]); r[7] = (short)f2bf(hi[3]);
  return r;
}

#define GLOAD16(g, l)                                                                  \
  __builtin_amdgcn_global_load_lds((const __attribute__((address_space(1))) void*)(g), \
                                   (__attribute__((address_space(3))) void*)(l), 16, 0, 0)

// ---------------------------------------------------------------- prep: X -> XcT bf16 [512][8192]
__global__ __launch_bounds__(256)
void prep_x(const float* __restrict__ x, unsigned short* __restrict__ xct) {
  __shared__ float tile[64][129];
  const int t  = threadIdx.x;
  const int m0 = blockIdx.x * 64;
  const int b  = blockIdx.y;
  const float* src = x + (size_t)b * (8192 * 128) + (size_t)m0 * 128;
#pragma unroll
  for (int i = 0; i < 32; ++i) {
    int e = t + i * 256;
    tile[e >> 7][e & 127] = src[e];
  }
  __syncthreads();
  const int f    = t >> 1;
  const int mseg = (t & 1) * 32;
  unsigned short* dst = xct + (size_t)(b * 128 + f) * 8192 + m0 + mseg;
#pragma unroll
  for (int i = 0; i < 4; ++i) {
    uint4 v;
    v.x = pack2(tile[mseg + i * 8 + 0][f], tile[mseg + i * 8 + 1][f]);
    v.y = pack2(tile[mseg + i * 8 + 2][f], tile[mseg + i * 8 + 3][f]);
    v.z = pack2(tile[mseg + i * 8 + 4][f], tile[mseg + i * 8 + 5][f]);
    v.w = pack2(tile[mseg + i * 8 + 6][f], tile[mseg + i * 8 + 7][f]);
    ((uint4*)dst)[i] = v;
  }
}

// ---------------------------------------------------------------- prep: W[fi][fo] -> WT bf16 [fo][fi]
struct WPtrs { const float* w[8]; };
__global__ __launch_bounds__(256)
void prep_w(WPtrs p, unsigned short* __restrict__ wt) {
  const int s = blockIdx.x;
  const float* W = p.w[s];
  unsigned short* dst = wt + s * 16384;
  for (int i = threadIdx.x; i < 16384; i += 256) {
    const int fi = i >> 7, fo = i & 127;
    dst[fo * 128 + fi] = f2bf(W[i]);
  }
}

// ---------------------------------------------------------------- fused branch GEMM
// Block: 128(m) x 128(n of 512), full K=8192, branch = blockIdx.z.
// LDS: A fp32 [2][128 rows][128B] chunk-swizzled (c^(r&7)); B bf16 [2][128][64B] (c^((r>>1)&3)).
struct FusedArgs {
  const float* L[4];
  const float* bias[4];
  const unsigned short* Bsrc;      // layer0: XcT (shared); layer1: H1T base
  unsigned long long bStride;      // per-branch elems: 0 (layer0) or 512*8192 (layer1)
  const unsigned short* WT;        // base of 8 W tiles; kernel adds (2*br+LAYER)*16384
  void* Dst;                       // layer0: H1T (ushort); layer1: out (float)
};

template <int LAYER>
__global__ __launch_bounds__(256, 3)
void gcn_fused(FusedArgs a) {
  extern __shared__ char smem[];
  char* Ab = smem;           // 2 x 16384 B
  char* Bb = smem + 32768;   // 2 x 8192 B

  const int t = threadIdx.x, lane = t & 63, wave = t >> 6;
  const int l15 = lane & 15;
  const int lk  = (lane >> 4) * 8;
  const int wm = (wave >> 1) * 64, wn = (wave & 1) * 64;
  const int mbase = blockIdx.x * 128, nb = blockIdx.y, br = blockIdx.z;

  const float* A = a.L[br];
  const unsigned short* Bsrc = a.Bsrc + (size_t)br * a.bStride;
  const unsigned short* WT = a.WT + (size_t)(2 * br + LAYER) * 16384;
  const float* bias = a.bias[br];

  // --- staging source addresses (pre-swizzled so linear gl_lds dest yields swizzled LDS) ---
  // A instr j(0..3): 8 rows; lane -> row wave*32+j*8+(l>>3), data chunk (l&7)^(l>>3)
  const float* aG = A + (size_t)(mbase + wave * 32 + (lane >> 3)) * 8192
                      + ((lane & 7) ^ (lane >> 3)) * 4;
  // B instr j(0..1): 16 rows; lane -> row wave*32+j*16+(l>>2), data chunk (l&3)^((l>>3)&3)
  const unsigned short* bG = Bsrc + (size_t)(nb * 128 + wave * 32 + (lane >> 2)) * 8192
                                  + (((lane & 3) ^ ((lane >> 3) & 3)) * 8);
  char* aL = Ab + (wave * 32) * 128;  // wave-uniform LDS dest bases
  char* bL = Bb + (wave * 32) * 64;

#define STAGE(buf, tt)                                                         \
  do {                                                                         \
    const float* ap = aG + (size_t)(tt) * 32;                                  \
    const unsigned short* bp = bG + (size_t)(tt) * 32;                         \
    GLOAD16(ap,                 aL + (buf) * 16384);                           \
    GLOAD16(ap + 8 * 8192,      aL + (buf) * 16384 + 1024);                    \
    GLOAD16(ap + 16 * 8192,     aL + (buf) * 16384 + 2048);                    \
    GLOAD16(ap + 24 * 8192,     aL + (buf) * 16384 + 3072);                    \
    GLOAD16(bp,                 bL + (buf) * 8192);                            \
    GLOAD16(bp + 16 * 8192,     bL + (buf) * 8192 + 1024);                     \
  } while (0)

  f32x4 acc[4][4];
#pragma unroll
  for (int i = 0; i < 4; ++i)
#pragma unroll
    for (int j = 0; j < 4; ++j) acc[i][j] = f32x4{0.f, 0.f, 0.f, 0.f};

  STAGE(0, 0);
  __syncthreads();

  // fragment-read byte offsets (swizzle applied on read side, matching storage)
  const int ac0 = (lane >> 4) * 2;            // A 16B-chunk pair base (c0, c0+1)
  const int axr = lane & 7;                   // A row-xor key (r&7 == lane&7 for our rows)
  const int bxr = (l15 >> 1) & 3;             // B row-xor key ((r>>1)&3)
  const int bc  = (lane >> 4) ^ bxr;          // B stored chunk

  for (int tt = 0; tt < 256; ++tt) {
    const int cur = tt & 1;
    if (tt < 255) STAGE(cur ^ 1, tt + 1);  // async into other buffer; drains at barrier

    {
      const char* ab = Ab + cur * 16384;
      const char* bb = Bb + cur * 8192;
      bf16x8 av[4], bv[4];
#pragma unroll
      for (int mi = 0; mi < 4; ++mi) {
        const int r = wm + mi * 16 + l15;
        f32x4 lo = *(const f32x4*)(ab + r * 128 + ((ac0 ^ axr) * 16));
        f32x4 hi = *(const f32x4*)(ab + r * 128 + (((ac0 + 1) ^ axr) * 16));
        av[mi] = cvt8(lo, hi);
      }
#pragma unroll
      for (int ni = 0; ni < 4; ++ni) {
        const int r = wn + ni * 16 + l15;
        bv[ni] = *(const bf16x8*)(bb + r * 64 + bc * 16);
      }
#pragma unroll
      for (int mi = 0; mi < 4; ++mi)
#pragma unroll
        for (int ni = 0; ni < 4; ++ni)
          acc[mi][ni] = __builtin_amdgcn_mfma_f32_16x16x32_bf16(av[mi], bv[ni], acc[mi][ni], 0, 0, 0);
    }
    __syncthreads();
  }
#undef STAGE

  // ---------------- epilogue: H = relu(S @ W + bias); S via LDS round-trip (bf16)
  unsigned short* S = (unsigned short*)smem;  // [128][136] pad -> 272B rows, 2-way banks
#pragma unroll
  for (int mi = 0; mi < 4; ++mi) {
#pragma unroll
    for (int ni = 0; ni < 4; ++ni) {
      const int row0 = wm + mi * 16 + (lane >> 4) * 4;
      const int col  = wn + ni * 16 + l15;
#pragma unroll
      for (int r = 0; r < 4; ++r) S[(row0 + r) * 136 + col] = f2bf(acc[mi][ni][r]);
    }
  }
  __syncthreads();

  f32x4 acc2[4][4];
#pragma unroll
  for (int ni = 0; ni < 4; ++ni) {
    const float bvv = bias[wn + ni * 16 + l15];
#pragma unroll
    for (int mi = 0; mi < 4; ++mi) acc2[mi][ni] = f32x4{bvv, bvv, bvv, bvv};
  }
#pragma unroll
  for (int kk = 0; kk < 4; ++kk) {
    bf16x8 av[4], wv[4];
#pragma unroll
    for (int mi = 0; mi < 4; ++mi)
      av[mi] = *(const bf16x8*)&S[(wm + mi * 16 + l15) * 136 + kk * 32 + lk];
#pragma unroll
    for (int ni = 0; ni < 4; ++ni)  // W fragments from global (32KB, L2-hot, block-wide reuse)
      wv[ni] = *(const bf16x8*)&WT[(wn + ni * 16 + l15) * 128 + kk * 32 + lk];
#pragma unroll
    for (int mi = 0; mi < 4; ++mi)
#pragma unroll
      for (int ni = 0; ni < 4; ++ni)
        acc2[mi][ni] = __builtin_amdgcn_mfma_f32_16x16x32_bf16(av[mi], wv[ni], acc2[mi][ni], 0, 0, 0);
  }

#pragma unroll
  for (int mi = 0; mi < 4; ++mi) {
#pragma unroll
    for (int ni = 0; ni < 4; ++ni) {
      const int row0 = wm + mi * 16 + (lane >> 4) * 4;
      const int col  = wn + ni * 16 + l15;
      const float v0 = fmaxf(acc2[mi][ni][0], 0.f);
      const float v1 = fmaxf(acc2[mi][ni][1], 0.f);
      const float v2 = fmaxf(acc2[mi][ni][2], 0.f);
      const float v3 = fmaxf(acc2[mi][ni][3], 0.f);
      if (LAYER == 0) {  // H1T bf16 [4br][512][8192], n-major for next layer's B
        unsigned short* Dst = (unsigned short*)a.Dst;
        uint2 pv;
        pv.x = pack2(v0, v1);
        pv.y = pack2(v2, v3);
        *(uint2*)(Dst + ((size_t)br * 512 + nb * 128 + col) * 8192 + mbase + row0) = pv;
      } else {           // out fp32 [4br][4batch][8192][128]
        float* Dst = (float*)a.Dst;
        const size_t base = (size_t)br * 4194304 + (size_t)nb * 1048576
                          + (size_t)(mbase + row0) * 128 + col;
        Dst[base      ] = v0;
        Dst[base + 128] = v1;
        Dst[base + 256] = v2;
        Dst[base + 384] = v3;
      }
    }
  }
}

// ---------------------------------------------------------------- launch
extern "C" void kernel_launch(void* const* d_in, const int* in_sizes, int n_in,
                              void* d_out, int out_size, void* d_ws, size_t ws_size,
                              hipStream_t stream) {
  // inputs: 0:x 1..4:L0..L3; W(b,l)=d_in[5+b*4+l*2], bias(b,l)=d_in[6+b*4+l*2]
  const float* x = (const float*)d_in[0];
  unsigned short* XcT = (unsigned short*)d_ws;             // [512][8192] bf16 (8 MiB)
  unsigned short* H1T = XcT + (size_t)512 * 8192;          // [4][512][8192] bf16 (32 MiB)
  unsigned short* WT  = H1T + (size_t)4 * 512 * 8192;      // [8][128][128] bf16 (256 KiB)
  float* out = (float*)d_out;

  prep_x<<<dim3(128, 4), 256, 0, stream>>>(x, XcT);

  WPtrs wp;
  for (int b = 0; b < 4; ++b) {
    wp.w[b * 2 + 0] = (const float*)d_in[5 + b * 4 + 0];
    wp.w[b * 2 + 1] = (const float*)d_in[5 + b * 4 + 2];
  }
  prep_w<<<8, 256, 0, stream>>>(wp, WT);

  FusedArgs a0, a1;
  for (int b = 0; b < 4; ++b) {
    a0.L[b] = (const float*)d_in[1 + b];
    a1.L[b] = (const float*)d_in[1 + b];
    a0.bias[b] = (const float*)d_in[6 + b * 4];      // layer 0 bias
    a1.bias[b] = (const float*)d_in[8 + b * 4];      // layer 1 bias
  }
  a0.Bsrc = XcT;  a0.bStride = 0;                    // all branches read XcT
  a1.Bsrc = H1T;  a1.bStride = (size_t)512 * 8192;   // per-branch H1
  a0.WT = WT;     a1.WT = WT;
  a0.Dst = (void*)H1T;
  a1.Dst = (void*)out;

  const size_t shmem = 49152;  // A 32KB + B 16KB; epilogue S 34.8KB overlays
  gcn_fused<0><<<dim3(64, 4, 4), 256, shmem, stream>>>(a0);
  gcn_fused<1><<<dim3(64, 4, 4), 256, shmem, stream>>>(a1);
}

// Round 5
// 1031.726 us; speedup vs baseline: 2.3113x; 1.1485x over previous
//
#include <hip/hip_runtime.h>
#include <stdint.h>

// GCN multi-branch, round 5.
// Key identity: relu((L@x)@W + b) == relu(L@(x@W) + b)  -> W-transform moved to input side.
// Pipeline: prep_w; small<1>: Z = x@W0b; big<0>: H1 = relu(L@Z+b0) (bf16 m-major);
//           small<0>: Z = H1@W1b;  big<1>: out = relu(L@Z+b1) (fp32).
// big: 256x256 tile, 8 waves, BK=32, 4-slot LDS ring (128KB), counted vmcnt(6),
//      raw s_barrier (1/tile), A fp32 reg-staged (2-deep) + swizzled ds_write,
//      B bf16 via pre-swizzled global_load_lds, setprio around MFMA clusters.

typedef short bf16x8 __attribute__((ext_vector_type(8)));
typedef float f32x4 __attribute__((ext_vector_type(4)));

static __device__ __forceinline__ unsigned short f2bf(float f) {
  __bf16 h = (__bf16)f;
  return __builtin_bit_cast(unsigned short, h);
}
static __device__ __forceinline__ unsigned int pack2(float a, float b) {
  return (unsigned int)f2bf(a) | ((unsigned int)f2bf(b) << 16);
}
static __device__ __forceinline__ bf16x8 cvt8(float4 lo, float4 hi) {
  bf16x8 r;
  r[0] = (short)f2bf(lo.x); r[1] = (short)f2bf(lo.y);
  r[2] = (short)f2bf(lo.z); r[3] = (short)f2bf(lo.w);
  r[4] = (short)f2bf(hi.x); r[5] = (short)f2bf(hi.y);
  r[6] = (short)f2bf(hi.z); r[7] = (short)f2bf(hi.w);
  return r;
}

#define GLOAD16(g, l)                                                                  \
  __builtin_amdgcn_global_load_lds((const __attribute__((address_space(1))) void*)(g), \
                                   (__attribute__((address_space(3))) void*)(l), 16, 0, 0)

// ---------------------------------------------------------------- prep: W[fi][fo] -> WT bf16 [fo][fi]
struct WPtrs { const float* w[8]; };
__global__ __launch_bounds__(256)
void prep_w(WPtrs p, unsigned short* __restrict__ wt) {
  const int s = blockIdx.x;
  const float* W = p.w[s];
  unsigned short* dst = wt + s * 16384;
  for (int i = threadIdx.x; i < 16384; i += 256) {
    const int fi = i >> 7, fo = i & 127;
    dst[fo * 128 + fi] = f2bf(W[i]);
  }
}

// ---------------------------------------------------------------- small GEMM: Z = A @ W  (K=128)
// AFP32=1: A = x fp32 [4batch][8192][128] (shared over br), W = W0[br]
// AFP32=0: A = H1 bf16 m-major [br][4batch][8192][128],      W = W1[br]
// Dst Z bf16 n-major [br][512][8192]. No bias, no relu.
template <int AFP32>
__global__ __launch_bounds__(256)
void small_gemm(const float* __restrict__ x, const unsigned short* __restrict__ H1m,
                const unsigned short* __restrict__ WT, unsigned short* __restrict__ Z) {
  __shared__ unsigned short Sa[128 * 136];  // A tile [128 m][128 k], pitch 136

  const int t = threadIdx.x, lane = t & 63, wave = t >> 6;
  const int l15 = lane & 15, lk = (lane >> 4) * 8;
  const int wm = (wave >> 1) * 64, wn = (wave & 1) * 64;
  const int mt = blockIdx.x, br = blockIdx.y;
  const int batch = mt >> 6, node0 = (mt & 63) * 128;

  {
    const int row = t >> 1, seg = (t & 1) * 64;
    if (AFP32) {
      const float4* src = (const float4*)(x + ((size_t)batch * 8192 + node0 + row) * 128 + seg);
      uint4* dst = (uint4*)&Sa[row * 136 + seg];
#pragma unroll
      for (int i = 0; i < 8; ++i) {
        float4 a = src[i * 2], b = src[i * 2 + 1];
        uint4 v;
        v.x = pack2(a.x, a.y); v.y = pack2(a.z, a.w);
        v.z = pack2(b.x, b.y); v.w = pack2(b.z, b.w);
        dst[i] = v;
      }
    } else {
      const uint4* src = (const uint4*)(H1m + ((size_t)(br * 4 + batch) * 8192 + node0 + row) * 128 + seg);
      uint4* dst = (uint4*)&Sa[row * 136 + seg];
#pragma unroll
      for (int i = 0; i < 8; ++i) dst[i] = src[i];
    }
  }
  __syncthreads();

  const unsigned short* WTb = WT + (size_t)(2 * br + (AFP32 ? 0 : 1)) * 16384;
  f32x4 acc[4][4];
#pragma unroll
  for (int i = 0; i < 4; ++i)
#pragma unroll
    for (int j = 0; j < 4; ++j) acc[i][j] = f32x4{0.f, 0.f, 0.f, 0.f};

#pragma unroll
  for (int kk = 0; kk < 4; ++kk) {
    bf16x8 av[4], wv[4];
#pragma unroll
    for (int mi = 0; mi < 4; ++mi)
      av[mi] = *(const bf16x8*)&Sa[(wm + mi * 16 + l15) * 136 + kk * 32 + lk];
#pragma unroll
    for (int ni = 0; ni < 4; ++ni)
      wv[ni] = *(const bf16x8*)&WTb[(wn + ni * 16 + l15) * 128 + kk * 32 + lk];
#pragma unroll
    for (int mi = 0; mi < 4; ++mi)
#pragma unroll
      for (int ni = 0; ni < 4; ++ni)
        acc[mi][ni] = __builtin_amdgcn_mfma_f32_16x16x32_bf16(av[mi], wv[ni], acc[mi][ni], 0, 0, 0);
  }

#pragma unroll
  for (int mi = 0; mi < 4; ++mi) {
#pragma unroll
    for (int ni = 0; ni < 4; ++ni) {
      const int row0 = wm + mi * 16 + (lane >> 4) * 4;
      const int col  = wn + ni * 16 + l15;  // fo
      uint2 pv;
      pv.x = pack2(acc[mi][ni][0], acc[mi][ni][1]);
      pv.y = pack2(acc[mi][ni][2], acc[mi][ni][3]);
      *(uint2*)(Z + ((size_t)br * 512 + batch * 128 + col) * 8192 + node0 + row0) = pv;
    }
  }
}

// ---------------------------------------------------------------- big GEMM: Dst = relu(L @ Z^T + b)
// 256x256 tile, BK=32, 256 K-tiles; LDS ring: A bf16 4x16KB @0, B bf16 4x16KB @65536.
struct BigArgs {
  const float* L[4];
  const float* bias[4];
  const unsigned short* Z;  // [br][512][8192] bf16 n-major
  void* Dst;                // LAYER0: H1 bf16 m-major; LAYER1: out fp32
};

template <int LAYER>
__global__ __launch_bounds__(512, 2)
void big_gemm(BigArgs a) {
  extern __shared__ char smem[];

  const int t = threadIdx.x, lane = t & 63, wave = t >> 6;
  const int l15 = lane & 15;
  const int wm = (wave >> 2) * 128, wn = (wave & 3) * 64;

  // bijective chunked XCD decode: xcd = bid&7 gets 32 contiguous works
  const int bid = blockIdx.x;
  const int work = (bid & 7) * 32 + (bid >> 3);
  const int nb = work & 1, mt = (work >> 1) & 31, br = work >> 6;
  const int mbase = mt * 256;

  const float* A = a.L[br];
  const float* bias = a.bias[br];
  const unsigned short* Zb = a.Z + (size_t)br * (512 * 8192);

  // ---- staging addresses ----
  // A reg-stage: lane -> row wave*32+(lane>>1), 16B-chunks c0=2*(lane&1), c0+1 (64B contiguous)
  const int c0 = 2 * (lane & 1);
  const int akey = (lane >> 2) & 3;  // == (row_local>>1)&3
  const float* aBase = A + (size_t)(mbase + wave * 32 + (lane >> 1)) * 8192 + c0 * 8;
  char* aLane = smem + (wave * 32 + (lane >> 1)) * 64;  // + slot + stored*16
  // B via global_load_lds, pre-swizzled source; LDS dest wave-uniform
  const unsigned short* bG = Zb + (size_t)(nb * 256 + wave * 32 + (lane >> 2)) * 8192
                                + ((lane & 3) ^ ((lane >> 3) & 3)) * 8;
  char* bWave = smem + 65536 + wave * 2048;  // + slot + j*1024

  // fragment-read swizzled chunk offset (same for A and B)
  const int aoff = (((lane >> 4) ^ ((lane >> 1) & 3)) & 7) * 16;

  f32x4 acc[8][4];
#pragma unroll
  for (int i = 0; i < 8; ++i)
#pragma unroll
    for (int j = 0; j < 4; ++j) acc[i][j] = f32x4{0.f, 0.f, 0.f, 0.f};

  float4 ra[4], rb[4];

#define GLB(s)                                              \
  do {                                                      \
    const unsigned short* bp = bG + (size_t)(s) * 32;       \
    char* bl = bWave + ((s) & 3) * 16384;                   \
    GLOAD16(bp, bl);                                        \
    GLOAD16(bp + 16 * 8192, bl + 1024);                     \
  } while (0)

#define LOADA(s, R)                                         \
  do {                                                      \
    const float* ap = aBase + (size_t)(s) * 32;             \
    R[0] = *(const float4*)(ap);                            \
    R[1] = *(const float4*)(ap + 4);                        \
    R[2] = *(const float4*)(ap + 8);                        \
    R[3] = *(const float4*)(ap + 12);                       \
  } while (0)

#define WRITEA(s, R)                                                        \
  do {                                                                      \
    char* al = aLane + ((s) & 3) * 16384;                                   \
    *(bf16x8*)(al + ((c0 ^ akey) * 16)) = cvt8(R[0], R[1]);                 \
    *(bf16x8*)(al + (((c0 + 1) ^ akey) * 16)) = cvt8(R[2], R[3]);           \
  } while (0)

#define MFMA_HALF(NLO)                                                                         \
  do {                                                                                         \
    __builtin_amdgcn_s_setprio(1);                                                             \
    _Pragma("unroll") for (int mi = 0; mi < 8; ++mi) {                                         \
      acc[mi][NLO] = __builtin_amdgcn_mfma_f32_16x16x32_bf16(av[mi], bv[0], acc[mi][NLO], 0, 0, 0); \
      acc[mi][NLO + 1] = __builtin_amdgcn_mfma_f32_16x16x32_bf16(av[mi], bv[1], acc[mi][NLO + 1], 0, 0, 0); \
    }                                                                                          \
    __builtin_amdgcn_s_setprio(0);                                                             \
  } while (0)

#define ITER(T_, PREV_, NEXT_, VMSTR_, DO_GLB_, DO_LOADA_, DO_WRITEA_)                  \
  do {                                                                                  \
    asm volatile("s_waitcnt lgkmcnt(0)" ::: "memory");                                  \
    __builtin_amdgcn_s_barrier();                                                       \
    asm volatile("" ::: "memory");                                                      \
    if (DO_GLB_) GLB((T_) + 3);                                                         \
    if (DO_LOADA_) LOADA((T_) + 2, NEXT_);                                              \
    const char* ab = smem + ((T_) & 3) * 16384;                                         \
    const char* bb = smem + 65536 + ((T_) & 3) * 16384;                                 \
    bf16x8 av[8], bv[2];                                                                \
    _Pragma("unroll") for (int mi = 0; mi < 8; ++mi)                                    \
        av[mi] = *(const bf16x8*)(ab + (wm + mi * 16 + l15) * 64 + aoff);               \
    bv[0] = *(const bf16x8*)(bb + (wn + l15) * 64 + aoff);                              \
    bv[1] = *(const bf16x8*)(bb + (wn + 16 + l15) * 64 + aoff);                         \
    MFMA_HALF(0);                                                                       \
    if (DO_WRITEA_) {                                                                   \
      asm volatile("s_waitcnt " VMSTR_ ::: "memory");                                   \
      WRITEA((T_) + 1, PREV_);                                                          \
    }                                                                                   \
    bv[0] = *(const bf16x8*)(bb + (wn + 32 + l15) * 64 + aoff);                         \
    bv[1] = *(const bf16x8*)(bb + (wn + 48 + l15) * 64 + aoff);                         \
    MFMA_HALF(2);                                                                       \
  } while (0)

  // ---- prologue: B(0..2) in flight, A(0) written, A(1) in rb ----
  GLB(0); GLB(1); GLB(2);
  LOADA(0, ra); LOADA(1, rb);
  WRITEA(0, ra);  // compiler inserts vmcnt wait for ra (forces B0..B2 + A0 landed)

  // ---- main loop: 256 K-tiles ----
  for (int tt = 0; tt < 252; tt += 2) {
    ITER(tt,     rb, ra, "vmcnt(6)", 1, 1, 1);
    ITER(tt + 1, ra, rb, "vmcnt(6)", 1, 1, 1);
  }
  ITER(252, rb, ra, "vmcnt(6)", 1, 1, 1);
  ITER(253, ra, rb, "vmcnt(4)", 0, 1, 1);
  ITER(254, rb, ra, "vmcnt(0)", 0, 0, 1);
  {  // tile 255: compute only
    asm volatile("s_waitcnt lgkmcnt(0)" ::: "memory");
    __builtin_amdgcn_s_barrier();
    asm volatile("" ::: "memory");
    const char* ab = smem + (255 & 3) * 16384;
    const char* bb = smem + 65536 + (255 & 3) * 16384;
    bf16x8 av[8], bv[2];
#pragma unroll
    for (int mi = 0; mi < 8; ++mi)
      av[mi] = *(const bf16x8*)(ab + (wm + mi * 16 + l15) * 64 + aoff);
    bv[0] = *(const bf16x8*)(bb + (wn + l15) * 64 + aoff);
    bv[1] = *(const bf16x8*)(bb + (wn + 16 + l15) * 64 + aoff);
    MFMA_HALF(0);
    bv[0] = *(const bf16x8*)(bb + (wn + 32 + l15) * 64 + aoff);
    bv[1] = *(const bf16x8*)(bb + (wn + 48 + l15) * 64 + aoff);
    MFMA_HALF(2);
  }
#undef ITER
#undef MFMA_HALF
#undef WRITEA
#undef LOADA
#undef GLB

  // ---- epilogue: bias + relu, two n-half passes through LDS for coalesced stores ----
  asm volatile("s_waitcnt lgkmcnt(0)" ::: "memory");
  __builtin_amdgcn_s_barrier();
  asm volatile("" ::: "memory");

  unsigned short* S16 = (unsigned short*)smem;  // [256][136] bf16 (LAYER0)
  float* S32 = (float*)smem;                    // [256][128] f32  (LAYER1)

#pragma unroll
  for (int h = 0; h < 2; ++h) {
    if (((wave >> 1) & 1) == h) {
#pragma unroll
      for (int mi = 0; mi < 8; ++mi) {
#pragma unroll
        for (int ni = 0; ni < 4; ++ni) {
          const int row0 = wm + mi * 16 + (lane >> 4) * 4;
          const int col  = (wave & 1) * 64 + ni * 16 + l15;  // 0..127 within half
          const float bvv = bias[col];
#pragma unroll
          for (int r = 0; r < 4; ++r) {
            const float v = fmaxf(acc[mi][ni][r] + bvv, 0.f);
            if (LAYER == 0) S16[(row0 + r) * 136 + col] = f2bf(v);
            else            S32[(row0 + r) * 128 + col] = v;
          }
        }
      }
    }
    __syncthreads();
    const int batch = nb * 2 + h;
    const int row = t >> 1, seg = (t & 1) * 64;
    if (LAYER == 0) {
      unsigned short* Dst = (unsigned short*)a.Dst;
      const uint4* src = (const uint4*)&S16[row * 136 + seg];
      uint4* dst = (uint4*)(Dst + ((size_t)(br * 4 + batch) * 8192 + mbase + row) * 128 + seg);
#pragma unroll
      for (int i = 0; i < 8; ++i) dst[i] = src[i];
    } else {
      float* Dst = (float*)a.Dst;
      const float4* src = (const float4*)&S32[row * 128 + seg];
      float4* dst = (float4*)(Dst + ((size_t)(br * 4 + batch) * 8192 + mbase + row) * 128 + seg);
#pragma unroll
      for (int i = 0; i < 16; ++i) dst[i] = src[i];
    }
    __syncthreads();
  }
}

// ---------------------------------------------------------------- launch
extern "C" void kernel_launch(void* const* d_in, const int* in_sizes, int n_in,
                              void* d_out, int out_size, void* d_ws, size_t ws_size,
                              hipStream_t stream) {
  // inputs: 0:x 1..4:L0..L3; W(b,l)=d_in[5+b*4+l*2], bias(b,l)=d_in[6+b*4+l*2]
  const float* x = (const float*)d_in[0];
  unsigned short* Z   = (unsigned short*)d_ws;               // [4][512][8192] bf16 (32 MiB)
  unsigned short* H1m = Z + (size_t)4 * 512 * 8192;          // [4][4][8192][128] bf16 (32 MiB)
  unsigned short* WT  = H1m + (size_t)4 * 4 * 8192 * 128;    // [8][128][128] bf16 (256 KiB)
  float* out = (float*)d_out;

  static int attr_done = 0;
  if (!attr_done) {  // host-side, idempotent, not a stream op (graph-capture safe)
    hipFuncSetAttribute((const void*)big_gemm<0>, hipFuncAttributeMaxDynamicSharedMemorySize, 131072);
    hipFuncSetAttribute((const void*)big_gemm<1>, hipFuncAttributeMaxDynamicSharedMemorySize, 131072);
    attr_done = 1;
  }

  WPtrs wp;
  for (int b = 0; b < 4; ++b) {
    wp.w[b * 2 + 0] = (const float*)d_in[5 + b * 4 + 0];
    wp.w[b * 2 + 1] = (const float*)d_in[5 + b * 4 + 2];
  }
  prep_w<<<8, 256, 0, stream>>>(wp, WT);

  BigArgs a0, a1;
  for (int b = 0; b < 4; ++b) {
    a0.L[b] = (const float*)d_in[1 + b];
    a1.L[b] = (const float*)d_in[1 + b];
    a0.bias[b] = (const float*)d_in[6 + b * 4];   // layer-0 bias
    a1.bias[b] = (const float*)d_in[8 + b * 4];   // layer-1 bias
  }
  a0.Z = Z; a0.Dst = (void*)H1m;
  a1.Z = Z; a1.Dst = (void*)out;

  // layer 0: Z = x@W0, H1 = relu(L@Z + b0)
  small_gemm<1><<<dim3(256, 4), 256, 0, stream>>>(x, nullptr, WT, Z);
  big_gemm<0><<<256, 512, 131072, stream>>>(a0);
  // layer 1: Z = H1@W1, out = relu(L@Z + b1)
  small_gemm<0><<<dim3(256, 4), 256, 0, stream>>>(nullptr, H1m, WT, Z);
  big_gemm<1><<<256, 512, 131072, stream>>>(a1);
}